// Round 2
// baseline (742.194 us; speedup 1.0000x reference)
//
#include <hip/hip_runtime.h>

#define SEQ 1024
#define BN  512
#define NT  64
#define NBLK 256   // 256 blocks x 1 wave x 2 batch items = 512

typedef float f2 __attribute__((ext_vector_type(2)));

__global__ void zero_out_kernel(float* o) { o[0] = 0.0f; }

#define RPT16(M) M(0) M(1) M(2) M(3) M(4) M(5) M(6) M(7) \
                 M(8) M(9) M(10) M(11) M(12) M(13) M(14) M(15)

// E rows 4k..4k+3 for this lane, as two NAMED float2 (static access only ->
// stays in VGPRs). Shared by both interleaved batches.
#define ED(k)                                                          \
  f2 E##k##_0 = { __expf(trans[(4*(k)+0) * NT + lane]),                \
                  __expf(trans[(4*(k)+1) * NT + lane]) };              \
  f2 E##k##_1 = { __expf(trans[(4*(k)+2) * NT + lane]),                \
                  __expf(trans[(4*(k)+3) * NT + lane]) };

// one prefetched float4 chunk -> two v_pk_fma_f32 into chains Aa,Bb
#define CH(X,k,Aa,Bb) {                                                \
    float4 v = r##X[k];                                                \
    f2 lo = { v.x, v.y };                                              \
    f2 hi = { v.z, v.w };                                              \
    Aa = __builtin_elementwise_fma(lo, E##k##_0, Aa);                  \
    Bb = __builtin_elementwise_fma(hi, E##k##_1, Bb);                  \
  }

// issue the 16 b128 LDS broadcasts of su##X into r##X; consumed one full
// compute phase (~200 cy) later -> DS latency hidden by the other batch
#define LD(X) {                                                        \
    const float4* su4_ = (const float4*)su##X;                         \
    _Pragma("unroll")                                                  \
    for (int k = 0; k < 16; ++k) r##X[k] = su4_[k];                    \
  }

// one recurrence step for batch X using the prefetched r##X registers
#define STEPC(X, t) {                                                  \
    const float em_t = em0##X;                                         \
    em0##X = em1##X; em1##X = em2##X; em2##X = em3##X;                 \
    int tn = (t) + 4; if (tn > SEQ - 1) tn = SEQ - 1;                  \
    em3##X = emis[(tn * BN + b##X) * NT + lane];                       \
    const int   pk   = pkC##X;                 /* prefetched t     */  \
    const int   tg_t = pk & 0xFFFF;                                    \
    const int   mk_t = pk >> 16;                                       \
    const float Trow = TrowC##X;               /* prefetched t     */  \
    int tp = (t) + 1; if (tp > SEQ - 1) tp = SEQ - 1;                  \
    pkC##X   = spk##X[tp];                     /* prefetch t+1     */  \
    TrowC##X = strans[tg_t * NT + lane];       /* prefetch t+1     */  \
    const float w = __expf(em_t);              /* off the u-chain  */  \
    f2 A0={0.f,0.f},A1={0.f,0.f},A2={0.f,0.f},A3={0.f,0.f};            \
    f2 B0={0.f,0.f},B1={0.f,0.f},B2={0.f,0.f},B3={0.f,0.f};            \
    CH(X, 0,A0,B0) CH(X, 1,A1,B1) CH(X, 2,A2,B2) CH(X, 3,A3,B3)        \
    CH(X, 4,A0,B0) CH(X, 5,A1,B1) CH(X, 6,A2,B2) CH(X, 7,A3,B3)        \
    CH(X, 8,A0,B0) CH(X, 9,A1,B1) CH(X,10,A2,B2) CH(X,11,A3,B3)        \
    CH(X,12,A0,B0) CH(X,13,A1,B1) CH(X,14,A2,B2) CH(X,15,A3,B3)        \
    f2 S = ((A0 + A1) + (A2 + A3)) + ((B0 + B1) + (B2 + B3));          \
    float s  = S.x + S.y;                                              \
    float sw = s * w;                                                  \
    if (mk_t) {                                /* wave-uniform */      \
        u##X = sw;                                                     \
        if (lane == tg_t) score##X += em_t + Trow;                     \
        lt##X = tg_t;                                                  \
    }                                                                  \
    if (((t) & 3) == 0) {                      /* deferred renorm */   \
        int e = (__builtin_amdgcn_readfirstlane(                       \
                     __float_as_int(u##X)) >> 23) & 255;               \
        u##X = ldexpf(u##X, 127 - e);                                  \
        esum##X += e - 127;                                            \
    }                                                                  \
    su##X[lane] = u##X;                        /* in-order DS pipe */  \
  }

#define INIT(X)                                                        \
    float em_0##X = emis[(0 * BN + b##X) * NT + lane];                 \
    int   tg0##X  = spk##X[0] & 0xFFFF;                                \
    float alpha0##X = startT[lane] + em_0##X;                          \
    float M##X = __int_as_float(__builtin_amdgcn_readfirstlane(        \
                     __float_as_int(alpha0##X)));                      \
    float u##X = __expf(alpha0##X - M##X);                             \
    float score##X = (lane == tg0##X) ? alpha0##X : 0.0f;              \
    int   lt##X  = tg0##X;                                             \
    int   esum##X = 0;                                                 \
    int   pkC##X   = spk##X[1];                                        \
    float TrowC##X = strans[tg0##X * NT + lane];                       \
    float em0##X = emis[(1 * BN + b##X) * NT + lane];                  \
    float em1##X = emis[(2 * BN + b##X) * NT + lane];                  \
    float em2##X = emis[(3 * BN + b##X) * NT + lane];                  \
    float em3##X = emis[(4 * BN + b##X) * NT + lane];                  \
    su##X[lane] = u##X;                                                \
    float4 r##X[16];

extern "C" __global__ __launch_bounds__(64, 1)
void crf_kernel(const float* __restrict__ emis,
                const int*   __restrict__ tags,
                const int*   __restrict__ mask,
                const float* __restrict__ startT,
                const float* __restrict__ endT,
                const float* __restrict__ trans,
                float* __restrict__ out)
{
    const int bA   = blockIdx.x;         // batch item A
    const int bB   = blockIdx.x + NBLK;  // batch item B
    const int lane = threadIdx.x;

    __shared__ __align__(16) float strans[NT * NT];
    __shared__ __align__(16) float suA[NT];
    __shared__ __align__(16) float suB[NT];
    __shared__ int spkA[SEQ];
    __shared__ int spkB[SEQ];

    // ---- one-time staging (single wave, in-order DS, no barriers) ----
    {
        const float4* t4 = (const float4*)trans;
        float4* s4 = (float4*)strans;
        #pragma unroll
        for (int k = 0; k < 16; ++k)
            s4[k * NT + lane] = t4[k * NT + lane];
    }
    #pragma unroll
    for (int c = 0; c < SEQ / NT; ++c) {
        int t = c * NT + lane;
        spkA[t] = (tags[t * BN + bA] & 0xFFFF) | (mask[t * BN + bA] << 16);
        spkB[t] = (tags[t * BN + bB] & 0xFFFF) | (mask[t * BN + bB] << 16);
    }
    __threadfence_block();

    // ---- E in registers: 32 named float2 (64 VGPRs), shared by A and B ----
    RPT16(ED)

    // ---- t = 0 init for both recurrences ----
    INIT(A)
    INIT(B)

    // prime the pipeline: A's broadcasts in flight across the loop head
    LD(A)

    // Software pipeline, 2 independent recurrences per wave:
    //   LD(B)    issue B's su broadcasts   (written at end of prev iter)
    //   STEPC(A) compute A from rA regs    (~200 cy -> hides B's DS latency)
    //   LD(A)    issue A's su broadcasts   (just written by STEPC(A))
    //   STEPC(B) compute B from rB regs    (~200 cy -> hides A's DS latency)
    for (int t = 1; t < SEQ; ++t) {
        LD(B)
        STEPC(A, t)
        LD(A)
        STEPC(B, t)
    }

    // ---- epilogue: both batches reduced, one atomic ----
    if (lane == ltA) scoreA += endT[lane];
    if (lane == ltB) scoreB += endT[lane];
    const float eT = __expf(endT[lane]);
    float vA = uA * eT, vB = uB * eT;
    float spA = scoreA, spB = scoreB;
    #pragma unroll
    for (int off = 32; off > 0; off >>= 1) {
        vA  += __shfl_xor(vA,  off, 64);
        vB  += __shfl_xor(vB,  off, 64);
        spA += __shfl_xor(spA, off, 64);
        spB += __shfl_xor(spB, off, 64);
    }
    if (lane == 0) {
        const float LN2 = 0.69314718055994531f;
        float llh = (spA - (MA + (float)esumA * LN2 + __logf(vA)))
                  + (spB - (MB + (float)esumB * LN2 + __logf(vB)));
        atomicAdd(out, llh);
    }
}

extern "C" void kernel_launch(void* const* d_in, const int* in_sizes, int n_in,
                              void* d_out, int out_size, void* d_ws, size_t ws_size,
                              hipStream_t stream)
{
    const float* emis   = (const float*)d_in[0];
    const int*   tags   = (const int*)  d_in[1];
    const int*   mask   = (const int*)  d_in[2];
    const float* startT = (const float*)d_in[3];
    const float* endT   = (const float*)d_in[4];
    const float* trans  = (const float*)d_in[5];
    float* out = (float*)d_out;

    zero_out_kernel<<<1, 1, 0, stream>>>(out);
    crf_kernel<<<dim3(NBLK), dim3(NT), 0, stream>>>(emis, tags, mask,
                                                    startT, endT, trans, out);
}

// Round 3
// 740.298 us; speedup vs baseline: 1.0026x; 1.0026x over previous
//
#include <hip/hip_runtime.h>

#define SEQ 1024
#define BN  512
#define NT  64
#define NBLK 256   // 256 blocks x 1 wave x 2 batch items = 512

typedef float f2 __attribute__((ext_vector_type(2)));

__global__ void zero_out_kernel(float* o) { o[0] = 0.0f; }

#define RPT16(M) M(0) M(1) M(2) M(3) M(4) M(5) M(6) M(7) \
                 M(8) M(9) M(10) M(11) M(12) M(13) M(14) M(15)

// E rows 4k..4k+3 for this lane, as two NAMED float2 (static access only ->
// stays in VGPRs). Shared by both interleaved batches.
#define ED(k)                                                          \
  f2 E##k##_0 = { __expf(trans[(4*(k)+0) * NT + lane]),                \
                  __expf(trans[(4*(k)+1) * NT + lane]) };              \
  f2 E##k##_1 = { __expf(trans[(4*(k)+2) * NT + lane]),                \
                  __expf(trans[(4*(k)+3) * NT + lane]) };

// staging buffers: 16 NAMED float4 per batch (NOT arrays -> guaranteed VGPRs;
// round-2's float4 r[16] arrays went to scratch at VGPR_Count=112)
#define RDECL(X) float4 r##X##0, r##X##1, r##X##2,  r##X##3,  r##X##4,  \
                        r##X##5, r##X##6, r##X##7,  r##X##8,  r##X##9,  \
                        r##X##10,r##X##11,r##X##12, r##X##13, r##X##14, \
                        r##X##15;

// issue the 16 b128 LDS broadcasts of su##X into named regs; consumed one
// full compute phase (~250 cy) later -> DS latency hidden by the other batch
#define LD(X) {                                                        \
    const float4* su4_ = (const float4*)su##X;                         \
    r##X##0  = su4_[0];  r##X##1  = su4_[1];                           \
    r##X##2  = su4_[2];  r##X##3  = su4_[3];                           \
    r##X##4  = su4_[4];  r##X##5  = su4_[5];                           \
    r##X##6  = su4_[6];  r##X##7  = su4_[7];                           \
    r##X##8  = su4_[8];  r##X##9  = su4_[9];                           \
    r##X##10 = su4_[10]; r##X##11 = su4_[11];                          \
    r##X##12 = su4_[12]; r##X##13 = su4_[13];                          \
    r##X##14 = su4_[14]; r##X##15 = su4_[15];                          \
  }

// one prefetched named float4 chunk -> two v_pk_fma_f32 into chains Aa,Bb
#define CH(X,k,Aa,Bb) {                                                \
    float4 v = r##X##k;                                                \
    f2 lo = { v.x, v.y };                                              \
    f2 hi = { v.z, v.w };                                              \
    Aa = __builtin_elementwise_fma(lo, E##k##_0, Aa);                  \
    Bb = __builtin_elementwise_fma(hi, E##k##_1, Bb);                  \
  }

// one recurrence step for batch X using the prefetched r##X## registers
#define STEPC(X, t) {                                                  \
    const float em_t = em0##X;                                         \
    em0##X = em1##X; em1##X = em2##X; em2##X = em3##X;                 \
    int tn = (t) + 4; if (tn > SEQ - 1) tn = SEQ - 1;                  \
    em3##X = emis[(tn * BN + b##X) * NT + lane];                       \
    const int   pk   = pkC##X;                 /* prefetched t     */  \
    const int   tg_t = pk & 0xFFFF;                                    \
    const int   mk_t = pk >> 16;                                       \
    const float Trow = TrowC##X;               /* prefetched t     */  \
    int tp = (t) + 1; if (tp > SEQ - 1) tp = SEQ - 1;                  \
    pkC##X   = spk##X[tp];                     /* prefetch t+1     */  \
    TrowC##X = strans[tg_t * NT + lane];       /* prefetch t+1     */  \
    const float w = __expf(em_t);              /* off the u-chain  */  \
    f2 A0={0.f,0.f},A1={0.f,0.f},A2={0.f,0.f},A3={0.f,0.f};            \
    f2 B0={0.f,0.f},B1={0.f,0.f},B2={0.f,0.f},B3={0.f,0.f};            \
    CH(X, 0,A0,B0) CH(X, 1,A1,B1) CH(X, 2,A2,B2) CH(X, 3,A3,B3)        \
    CH(X, 4,A0,B0) CH(X, 5,A1,B1) CH(X, 6,A2,B2) CH(X, 7,A3,B3)        \
    CH(X, 8,A0,B0) CH(X, 9,A1,B1) CH(X,10,A2,B2) CH(X,11,A3,B3)        \
    CH(X,12,A0,B0) CH(X,13,A1,B1) CH(X,14,A2,B2) CH(X,15,A3,B3)        \
    f2 S = ((A0 + A1) + (A2 + A3)) + ((B0 + B1) + (B2 + B3));          \
    float s  = S.x + S.y;                                              \
    float sw = s * w;                                                  \
    if (mk_t) {                                /* wave-uniform */      \
        u##X = sw;                                                     \
        if (lane == tg_t) score##X += em_t + Trow;                     \
        lt##X = tg_t;                                                  \
    }                                                                  \
    if (((t) & 3) == 0) {                      /* deferred renorm */   \
        int e = (__builtin_amdgcn_readfirstlane(                       \
                     __float_as_int(u##X)) >> 23) & 255;               \
        u##X = ldexpf(u##X, 127 - e);                                  \
        esum##X += e - 127;                                            \
    }                                                                  \
    su##X[lane] = u##X;                        /* in-order DS pipe */  \
  }

#define INIT(X)                                                        \
    float em_0##X = emis[(0 * BN + b##X) * NT + lane];                 \
    int   tg0##X  = spk##X[0] & 0xFFFF;                                \
    float alpha0##X = startT[lane] + em_0##X;                          \
    float M##X = __int_as_float(__builtin_amdgcn_readfirstlane(        \
                     __float_as_int(alpha0##X)));                      \
    float u##X = __expf(alpha0##X - M##X);                             \
    float score##X = (lane == tg0##X) ? alpha0##X : 0.0f;              \
    int   lt##X  = tg0##X;                                             \
    int   esum##X = 0;                                                 \
    int   pkC##X   = spk##X[1];                                        \
    float TrowC##X = strans[tg0##X * NT + lane];                       \
    float em0##X = emis[(1 * BN + b##X) * NT + lane];                  \
    float em1##X = emis[(2 * BN + b##X) * NT + lane];                  \
    float em2##X = emis[(3 * BN + b##X) * NT + lane];                  \
    float em3##X = emis[(4 * BN + b##X) * NT + lane];                  \
    su##X[lane] = u##X;                                                \
    RDECL(X)

extern "C" __global__ __launch_bounds__(64, 1)
void crf_kernel(const float* __restrict__ emis,
                const int*   __restrict__ tags,
                const int*   __restrict__ mask,
                const float* __restrict__ startT,
                const float* __restrict__ endT,
                const float* __restrict__ trans,
                float* __restrict__ out)
{
    const int bA   = blockIdx.x;         // batch item A
    const int bB   = blockIdx.x + NBLK;  // batch item B
    const int lane = threadIdx.x;

    __shared__ __align__(16) float strans[NT * NT];
    __shared__ __align__(16) float suA[NT];
    __shared__ __align__(16) float suB[NT];
    __shared__ int spkA[SEQ];
    __shared__ int spkB[SEQ];

    // ---- one-time staging (single wave, in-order DS, no barriers) ----
    {
        const float4* t4 = (const float4*)trans;
        float4* s4 = (float4*)strans;
        #pragma unroll
        for (int k = 0; k < 16; ++k)
            s4[k * NT + lane] = t4[k * NT + lane];
    }
    #pragma unroll
    for (int c = 0; c < SEQ / NT; ++c) {
        int t = c * NT + lane;
        spkA[t] = (tags[t * BN + bA] & 0xFFFF) | (mask[t * BN + bA] << 16);
        spkB[t] = (tags[t * BN + bB] & 0xFFFF) | (mask[t * BN + bB] << 16);
    }
    __threadfence_block();

    // ---- E in registers: 32 named float2 (64 VGPRs), shared by A and B ----
    RPT16(ED)

    // ---- t = 0 init for both recurrences ----
    INIT(A)
    INIT(B)

    // prime the pipeline: A's broadcasts in flight across the loop head
    LD(A)

    // Software pipeline, 2 independent recurrences per wave:
    //   LD(B)    issue B's su broadcasts   (suB written at end of prev iter)
    //   STEPC(A) compute A from rA regs    (~250 cy -> hides B's DS latency)
    //   LD(A)    issue A's su broadcasts   (suA just written by STEPC(A))
    //   STEPC(B) compute B from rB regs    (~250 cy -> hides A's DS latency)
    for (int t = 1; t < SEQ; ++t) {
        LD(B)
        STEPC(A, t)
        LD(A)
        STEPC(B, t)
    }

    // ---- epilogue: both batches reduced, one atomic ----
    if (lane == ltA) scoreA += endT[lane];
    if (lane == ltB) scoreB += endT[lane];
    const float eT = __expf(endT[lane]);
    float vA = uA * eT, vB = uB * eT;
    float spA = scoreA, spB = scoreB;
    #pragma unroll
    for (int off = 32; off > 0; off >>= 1) {
        vA  += __shfl_xor(vA,  off, 64);
        vB  += __shfl_xor(vB,  off, 64);
        spA += __shfl_xor(spA, off, 64);
        spB += __shfl_xor(spB, off, 64);
    }
    if (lane == 0) {
        const float LN2 = 0.69314718055994531f;
        float llh = (spA - (MA + (float)esumA * LN2 + __logf(vA)))
                  + (spB - (MB + (float)esumB * LN2 + __logf(vB)));
        atomicAdd(out, llh);
    }
}

extern "C" void kernel_launch(void* const* d_in, const int* in_sizes, int n_in,
                              void* d_out, int out_size, void* d_ws, size_t ws_size,
                              hipStream_t stream)
{
    const float* emis   = (const float*)d_in[0];
    const int*   tags   = (const int*)  d_in[1];
    const int*   mask   = (const int*)  d_in[2];
    const float* startT = (const float*)d_in[3];
    const float* endT   = (const float*)d_in[4];
    const float* trans  = (const float*)d_in[5];
    float* out = (float*)d_out;

    zero_out_kernel<<<1, 1, 0, stream>>>(out);
    crf_kernel<<<dim3(NBLK), dim3(NT), 0, stream>>>(emis, tags, mask,
                                                    startT, endT, trans, out);
}

// Round 4
// 628.513 us; speedup vs baseline: 1.1809x; 1.1779x over previous
//
#include <hip/hip_runtime.h>

#define SEQ 1024
#define BN  512
#define NT  64
#define WPB 4          // waves per block (split of the i-dimension)
#define IPW 16         // transition rows per wave

__global__ void zero_out_kernel(float* o) { o[0] = 0.0f; }

// lane-broadcast via v_readlane (index may be SGPR): no memory latency
__device__ __forceinline__ float rlf(float v, int l) {
    return __int_as_float(__builtin_amdgcn_readlane(__float_as_int(v), l));
}

extern "C" __global__ __launch_bounds__(256, 2)
void crf_kernel(const float* __restrict__ emis,
                const int*   __restrict__ tags,
                const int*   __restrict__ mask,
                const float* __restrict__ startT,
                const float* __restrict__ endT,
                const float* __restrict__ trans,
                float* __restrict__ out)
{
    const int b    = blockIdx.x;
    const int tid  = threadIdx.x;
    const int lane = tid & 63;
    const int wv   = tid >> 6;        // wave id 0..3
    const int sb   = wv * IPW;        // this wave's transition-row base

    __shared__ __align__(16) float strans[NT * NT];   // numerator Trow lookups
    __shared__ __align__(16) float part[2][WPB][NT];  // ping-pong partial sums
    __shared__ int spk[SEQ];                          // tag | mask<<16

    // ---- one-time staging, all 256 threads ----
    {
        const float4* t4 = (const float4*)trans;
        float4* s4 = (float4*)strans;
        #pragma unroll
        for (int k = 0; k < 4; ++k)
            s4[k * 256 + tid] = t4[k * 256 + tid];
    }
    #pragma unroll
    for (int c = 0; c < SEQ / 256; ++c) {
        int t = c * 256 + tid;
        spk[t] = (tags[t * BN + b] & 0xFFFF) | (mask[t * BN + b] << 16);
    }
    __syncthreads();

    // ---- E rows sb..sb+15, cols = lane: 16 named scalars (16 VGPRs) ----
#define EDECL(r) const float E##r = __expf(trans[(sb + (r)) * NT + lane]);
    EDECL(0)  EDECL(1)  EDECL(2)  EDECL(3)
    EDECL(4)  EDECL(5)  EDECL(6)  EDECL(7)
    EDECL(8)  EDECL(9)  EDECL(10) EDECL(11)
    EDECL(12) EDECL(13) EDECL(14) EDECL(15)
#undef EDECL

    // ---- t = 0 init (all waves redundantly; score only on wave 0) ----
    float em_0   = emis[(0 * BN + b) * NT + lane];
    int   tg0    = spk[0] & 0xFFFF;
    float alpha0 = startT[lane] + em_0;
    float M = __int_as_float(__builtin_amdgcn_readfirstlane(__float_as_int(alpha0)));
    float u = __expf(alpha0 - M);     // identical in every wave, every step
    float score = (wv == 0 && lane == tg0) ? alpha0 : 0.0f;
    int   lt    = tg0;
    int   esum  = 0;

    int   pkC   = spk[1];
    float TrowC = (wv == 0) ? strans[tg0 * NT + lane] : 0.0f;

    // depth-4 emission prefetch (vmcnt is never drained by the raw barrier)
    float emA = emis[(1 * BN + b) * NT + lane];
    float emB = emis[(2 * BN + b) * NT + lane];
    float emC = emis[(3 * BN + b) * NT + lane];
    float emD = emis[(4 * BN + b) * NT + lane];

    for (int t = 1; t < SEQ; ++t) {
        const float em_t = emA;
        emA = emB; emB = emC; emC = emD;
        int tn = t + 4; if (tn > SEQ - 1) tn = SEQ - 1;
        emD = emis[(tn * BN + b) * NT + lane];

        const int   pk   = pkC;                  // prefetched last iteration
        const int   tg_t = pk & 0xFFFF;
        const int   mk_t = pk >> 16;
        const float Trow = TrowC;

        const float wm = __expf(em_t);           // off the u-chain

        // 16-term partial: readlane broadcasts of own u x E rows in VGPRs
        float a0 = 0.f, a1 = 0.f, a2 = 0.f, a3 = 0.f;
#define FMA4(r0,r1,r2,r3)                            \
        a0 = fmaf(rlf(u, sb + r0), E##r0, a0);       \
        a1 = fmaf(rlf(u, sb + r1), E##r1, a1);       \
        a2 = fmaf(rlf(u, sb + r2), E##r2, a2);       \
        a3 = fmaf(rlf(u, sb + r3), E##r3, a3);
        FMA4(0,1,2,3)  FMA4(4,5,6,7)  FMA4(8,9,10,11)  FMA4(12,13,14,15)
#undef FMA4
        const float p = (a0 + a1) + (a2 + a3);
        part[t & 1][wv][lane] = p;               // stride-1, conflict-free

        // numerator on wave 0 only (hidden under the exchange)
        if (wv == 0 && mk_t && lane == tg_t) score += em_t + Trow;

        // drain DS only (partial write visible); vmem prefetch stays in flight
        asm volatile("s_waitcnt lgkmcnt(0)" ::: "memory");
        __builtin_amdgcn_s_barrier();

        const float p0 = part[t & 1][0][lane];
        const float p1 = part[t & 1][1][lane];
        const float p2 = part[t & 1][2][lane];
        const float p3 = part[t & 1][3][lane];

        // next-step prefetches issued behind the partial reads
        int tp = t + 1; if (tp > SEQ - 1) tp = SEQ - 1;
        pkC = spk[tp];
        if (wv == 0) TrowC = strans[tg_t * NT + lane];

        // identical op order in every wave -> u stays bitwise-identical
        const float s  = (p0 + p1) + (p2 + p3);
        const float sw = s * wm;
        if (mk_t) { u = sw; lt = tg_t; }         // wave-uniform select

        if ((t & 3) == 0) {                      // deferred exact renorm
            int e = (__builtin_amdgcn_readfirstlane(__float_as_int(u)) >> 23) & 255;
            u = ldexpf(u, 127 - e);
            esum += e - 127;
        }
    }

    // ---- epilogue: wave 0 owns the full result ----
    if (wv == 0) {
        if (lane == lt) score += endT[lane];
        float v  = u * __expf(endT[lane]);
        float sp = score;
        #pragma unroll
        for (int off = 32; off > 0; off >>= 1) {
            v  += __shfl_xor(v,  off, 64);
            sp += __shfl_xor(sp, off, 64);
        }
        if (lane == 0) {
            float denom = M + (float)esum * 0.69314718055994531f + __logf(v);
            atomicAdd(out, sp - denom);
        }
    }
}

extern "C" void kernel_launch(void* const* d_in, const int* in_sizes, int n_in,
                              void* d_out, int out_size, void* d_ws, size_t ws_size,
                              hipStream_t stream)
{
    const float* emis   = (const float*)d_in[0];
    const int*   tags   = (const int*)  d_in[1];
    const int*   mask   = (const int*)  d_in[2];
    const float* startT = (const float*)d_in[3];
    const float* endT   = (const float*)d_in[4];
    const float* trans  = (const float*)d_in[5];
    float* out = (float*)d_out;

    zero_out_kernel<<<1, 1, 0, stream>>>(out);
    crf_kernel<<<dim3(BN), dim3(256), 0, stream>>>(emis, tags, mask,
                                                   startT, endT, trans, out);
}

// Round 5
// 605.245 us; speedup vs baseline: 1.2263x; 1.0384x over previous
//
#include <hip/hip_runtime.h>

#define SEQ 1024
#define BN  512
#define NT  64
#define NBLK 256   // 256 blocks x 1 wave x 2 chains = 512 batch items

typedef float f2 __attribute__((ext_vector_type(2)));

__global__ void zero_out_kernel(float* o) { o[0] = 0.0f; }

#define RPT16(M) M(0) M(1) M(2) M(3) M(4) M(5) M(6) M(7) \
                 M(8) M(9) M(10) M(11) M(12) M(13) M(14) M(15)

// E rows 4k..4k+3 (cols = lane) as two NAMED f2 -> VGPRs, shared by chains
#define ED(k)                                                          \
  f2 E##k##_0 = { __expf(trans[(4*(k)+0) * NT + lane]),                \
                  __expf(trans[(4*(k)+1) * NT + lane]) };              \
  f2 E##k##_1 = { __expf(trans[(4*(k)+2) * NT + lane]),                \
                  __expf(trans[(4*(k)+3) * NT + lane]) };

// consume chunk k of chain X into accumulator pair (Aa,Bb): 2 v_pk_fma_f32
#define FC(X,k,Aa,Bb) {                                                \
    f2 lo = { c##X##k.x, c##X##k.y };                                  \
    f2 hi = { c##X##k.z, c##X##k.w };                                  \
    Aa = __builtin_elementwise_fma(lo, E##k##_0, Aa);                  \
    Bb = __builtin_elementwise_fma(hi, E##k##_1, Bb);                  \
  }

#define INIT(X)                                                        \
    float em_0##X = emis[(0 * BN + b##X) * NT + lane];                 \
    int   tg0##X  = spk##X[0] & 0xFFFF;                                \
    float alpha0##X = startT[lane] + em_0##X;                          \
    float M##X = __int_as_float(__builtin_amdgcn_readfirstlane(        \
                     __float_as_int(alpha0##X)));                      \
    float u##X = __expf(alpha0##X - M##X);                             \
    float score##X = (lane == tg0##X) ? alpha0##X : 0.0f;              \
    int   lt##X  = tg0##X;                                             \
    int   esum##X = 0;                                                 \
    int   pkC##X   = spk##X[1];                                        \
    float TrowC##X = strans[tg0##X * NT + lane];                       \
    float em0##X = emis[(1 * BN + b##X) * NT + lane];                  \
    float em1##X = emis[(2 * BN + b##X) * NT + lane];                  \
    float em2##X = emis[(3 * BN + b##X) * NT + lane];                  \
    float em3##X = emis[(4 * BN + b##X) * NT + lane];                  \
    su##X[lane] = u##X;

extern "C" __global__ __launch_bounds__(64, 1)
void crf_kernel(const float* __restrict__ emis,
                const int*   __restrict__ tags,
                const int*   __restrict__ mask,
                const float* __restrict__ startT,
                const float* __restrict__ endT,
                const float* __restrict__ trans,
                float* __restrict__ out)
{
    const int bA   = blockIdx.x;         // chain A batch item
    const int bB   = blockIdx.x + NBLK;  // chain B batch item
    const int lane = threadIdx.x;

    __shared__ __align__(16) float strans[NT * NT];
    __shared__ __align__(16) float suA[NT];
    __shared__ __align__(16) float suB[NT];
    __shared__ int spkA[SEQ];
    __shared__ int spkB[SEQ];

    // ---- one-time staging (single wave, in-order DS, no barriers) ----
    {
        const float4* t4 = (const float4*)trans;
        float4* s4 = (float4*)strans;
        #pragma unroll
        for (int k = 0; k < 16; ++k)
            s4[k * NT + lane] = t4[k * NT + lane];
    }
    #pragma unroll
    for (int c = 0; c < SEQ / NT; ++c) {
        int t = c * NT + lane;
        spkA[t] = (tags[t * BN + bA] & 0xFFFF) | (mask[t * BN + bA] << 16);
        spkB[t] = (tags[t * BN + bB] & 0xFFFF) | (mask[t * BN + bB] << 16);
    }
    __threadfence_block();

    // ---- E in registers: 32 named f2 (64 VGPRs), shared by both chains ----
    RPT16(ED)

    // ---- t = 0 init for both chains ----
    INIT(A)
    INIT(B)

    #pragma unroll 2
    for (int t = 1; t < SEQ; ++t) {
        // ---- emissions rotate + depth-4 prefetch (only vmem in loop) ----
        const float emtA = em0A; em0A = em1A; em1A = em2A; em2A = em3A;
        const float emtB = em0B; em0B = em1B; em1B = em2B; em2B = em3B;
        int tn = t + 4; if (tn > SEQ - 1) tn = SEQ - 1;
        em3A = emis[(tn * BN + bA) * NT + lane];
        em3B = emis[(tn * BN + bB) * NT + lane];

        const int   pkA = pkCA, pkB = pkCB;   // prefetched last iteration
        const int   tgA = pkA & 0xFFFF, mkA = pkA >> 16;
        const int   tgB = pkB & 0xFFFF, mkB = pkB >> 16;
        const float TrA = TrowCA,       TrB = TrowCB;

        const float4* suA4 = (const float4*)suA;
        const float4* suB4 = (const float4*)suB;

        // ---- issue chain A's 16 broadcast b128 reads, grouped.
        // suA was written BEFORE the ~150cy B-phase of the previous
        // iteration, so this round trip is already largely covered.
        float4 cA0  = suA4[0],  cA1  = suA4[1],  cA2  = suA4[2],  cA3  = suA4[3];
        float4 cA4  = suA4[4],  cA5  = suA4[5],  cA6  = suA4[6],  cA7  = suA4[7];
        float4 cA8  = suA4[8],  cA9  = suA4[9],  cA10 = suA4[10], cA11 = suA4[11];
        float4 cA12 = suA4[12], cA13 = suA4[13], cA14 = suA4[14], cA15 = suA4[15];

        // next-step control prefetch (b32s queue behind A's reads; consumed
        // next iteration, ~500 cy away)
        int tp = t + 1; if (tp > SEQ - 1) tp = SEQ - 1;
        pkCA   = spkA[tp];
        TrowCA = strans[tgA * NT + lane];
        pkCB   = spkB[tp];
        TrowCB = strans[tgB * NT + lane];

        const float wAx = __expf(emtA);       // off the u-chain
        const float wBx = __expf(emtB);

        // ---- consume A chunk-by-chunk, issuing B's read k right after
        // chunk k of A dies: disjoint lifetimes -> peak staging ~1 set
        float4 cB0, cB1, cB2, cB3, cB4, cB5, cB6, cB7;
        float4 cB8, cB9, cB10, cB11, cB12, cB13, cB14, cB15;
        f2 A0={0.f,0.f},A1={0.f,0.f},A2={0.f,0.f},A3={0.f,0.f};
        f2 B0={0.f,0.f},B1={0.f,0.f},B2={0.f,0.f},B3={0.f,0.f};
        FC(A, 0,A0,B0)  cB0  = suB4[0];
        FC(A, 1,A1,B1)  cB1  = suB4[1];
        FC(A, 2,A2,B2)  cB2  = suB4[2];
        FC(A, 3,A3,B3)  cB3  = suB4[3];
        FC(A, 4,A0,B0)  cB4  = suB4[4];
        FC(A, 5,A1,B1)  cB5  = suB4[5];
        FC(A, 6,A2,B2)  cB6  = suB4[6];
        FC(A, 7,A3,B3)  cB7  = suB4[7];
        FC(A, 8,A0,B0)  cB8  = suB4[8];
        FC(A, 9,A1,B1)  cB9  = suB4[9];
        FC(A,10,A2,B2)  cB10 = suB4[10];
        FC(A,11,A3,B3)  cB11 = suB4[11];
        FC(A,12,A0,B0)  cB12 = suB4[12];
        FC(A,13,A1,B1)  cB13 = suB4[13];
        FC(A,14,A2,B2)  cB14 = suB4[14];
        FC(A,15,A3,B3)  cB15 = suB4[15];

        // ---- chain A tail: tree, select, renorm, publish u for t+1 ----
        {
            f2 SA = ((A0 + A1) + (A2 + A3)) + ((B0 + B1) + (B2 + B3));
            float sA  = SA.x + SA.y;
            float swA = sA * wAx;
            if (mkA) {                         // wave-uniform
                uA = swA;
                if (lane == tgA) scoreA += emtA + TrA;
                ltA = tgA;
            }
            if ((t & 3) == 0) {                // deferred exact renorm
                int e = (__builtin_amdgcn_readfirstlane(
                             __float_as_int(uA)) >> 23) & 255;
                uA = ldexpf(uA, 127 - e);
                esumA += e - 127;
            }
            suA[lane] = uA;                    // BEFORE B phase: next iter's
        }                                      // A-reads hide under B compute

        // ---- consume B (reads arrived during A's consumption) ----
        {
            f2 P0={0.f,0.f},P1={0.f,0.f},P2={0.f,0.f},P3={0.f,0.f};
            f2 Q0={0.f,0.f},Q1={0.f,0.f},Q2={0.f,0.f},Q3={0.f,0.f};
            FC(B, 0,P0,Q0) FC(B, 1,P1,Q1) FC(B, 2,P2,Q2) FC(B, 3,P3,Q3)
            FC(B, 4,P0,Q0) FC(B, 5,P1,Q1) FC(B, 6,P2,Q2) FC(B, 7,P3,Q3)
            FC(B, 8,P0,Q0) FC(B, 9,P1,Q1) FC(B,10,P2,Q2) FC(B,11,P3,Q3)
            FC(B,12,P0,Q0) FC(B,13,P1,Q1) FC(B,14,P2,Q2) FC(B,15,P3,Q3)
            f2 SB = ((P0 + P1) + (P2 + P3)) + ((Q0 + Q1) + (Q2 + Q3));
            float sB  = SB.x + SB.y;
            float swB = sB * wBx;
            if (mkB) {
                uB = swB;
                if (lane == tgB) scoreB += emtB + TrB;
                ltB = tgB;
            }
            if ((t & 3) == 0) {
                int e = (__builtin_amdgcn_readfirstlane(
                             __float_as_int(uB)) >> 23) & 255;
                uB = ldexpf(uB, 127 - e);
                esumB += e - 127;
            }
            suB[lane] = uB;                    // read mid-next-iteration
        }
    }

    // ---- epilogue: both chains reduced, one atomic ----
    if (lane == ltA) scoreA += endT[lane];
    if (lane == ltB) scoreB += endT[lane];
    const float eT = __expf(endT[lane]);
    float vA = uA * eT, vB = uB * eT;
    float spA = scoreA, spB = scoreB;
    #pragma unroll
    for (int off = 32; off > 0; off >>= 1) {
        vA  += __shfl_xor(vA,  off, 64);
        vB  += __shfl_xor(vB,  off, 64);
        spA += __shfl_xor(spA, off, 64);
        spB += __shfl_xor(spB, off, 64);
    }
    if (lane == 0) {
        const float LN2 = 0.69314718055994531f;
        float llh = (spA - (MA + (float)esumA * LN2 + __logf(vA)))
                  + (spB - (MB + (float)esumB * LN2 + __logf(vB)));
        atomicAdd(out, llh);
    }
}

extern "C" void kernel_launch(void* const* d_in, const int* in_sizes, int n_in,
                              void* d_out, int out_size, void* d_ws, size_t ws_size,
                              hipStream_t stream)
{
    const float* emis   = (const float*)d_in[0];
    const int*   tags   = (const int*)  d_in[1];
    const int*   mask   = (const int*)  d_in[2];
    const float* startT = (const float*)d_in[3];
    const float* endT   = (const float*)d_in[4];
    const float* trans  = (const float*)d_in[5];
    float* out = (float*)d_out;

    zero_out_kernel<<<1, 1, 0, stream>>>(out);
    crf_kernel<<<dim3(NBLK), dim3(NT), 0, stream>>>(emis, tags, mask,
                                                    startT, endT, trans, out);
}